// Round 6
// baseline (2018.711 us; speedup 1.0000x reference)
//
#include <hip/hip_runtime.h>
#include <hip/hip_bf16.h>

#define NN 100000        // nodes per type
#define NE 1000000       // edges per relation
#define FI 128
#define FO 64
#define CHB 98           // ceil(NN/1024) scan chunks

typedef unsigned short u16;

__device__ __forceinline__ float bf2f(u16 u) {
    unsigned int v = ((unsigned int)u) << 16;
    return __uint_as_float(v);
}
__device__ __forceinline__ u16 f2bf(float f) {
    __hip_bfloat16 h = __float2bfloat16(f);
    return *(u16*)&h;
}

// ---------------- projection + attention-logit kernel ----------------
__global__ __launch_bounds__(256) void proj_kernel(
    const float* __restrict__ x, const float* __restrict__ W, const float* __restrict__ b,
    const float* __restrict__ a0, const float* __restrict__ a1,
    const float* __restrict__ a2, const float* __restrict__ a3,
    u16* __restrict__ hout, float* __restrict__ al)
{
    __shared__ float Wl[FI * FO];
    for (int i = threadIdx.x; i < FI * FO; i += 256) Wl[i] = W[i];
    __syncthreads();

    const int lane = threadIdx.x & 63;
    const int wid  = threadIdx.x >> 6;
    const int gw   = blockIdx.x * 4 + wid;
    const int nw   = gridDim.x * 4;
    const int head = lane >> 4;

    const float bv  = b[lane];
    const float av0 = a0[lane];
    const float av1 = a1[lane];
    const float av2 = a2[lane];
    const float av3 = a3[lane];

    for (int n = gw; n < NN; n += nw) {
        const float x0 = x[n * FI + lane];
        const float x1 = x[n * FI + 64 + lane];
        float acc = bv;
#pragma unroll
        for (int k = 0; k < 64; ++k)
            acc = fmaf(__shfl(x0, k), Wl[k * FO + lane], acc);
#pragma unroll
        for (int k = 0; k < 64; ++k)
            acc = fmaf(__shfl(x1, k), Wl[(64 + k) * FO + lane], acc);

        hout[n * FO + lane] = f2bf(acc);

        float p0 = acc * av0, p1 = acc * av1, p2 = acc * av2, p3 = acc * av3;
#pragma unroll
        for (int off = 1; off < 16; off <<= 1) {
            p0 += __shfl_xor(p0, off);
            p1 += __shfl_xor(p1, off);
            p2 += __shfl_xor(p2, off);
            p3 += __shfl_xor(p3, off);
        }
        if ((lane & 15) == 0) {
            al[0 * NN * 4 + n * 4 + head] = p0;
            al[1 * NN * 4 + n * 4 + head] = p1;
            al[2 * NN * 4 + n * 4 + head] = p2;
            al[3 * NN * 4 + n * 4 + head] = p3;
        }
    }
}

// ---------------- CSR build: histogram ----------------
__global__ __launch_bounds__(256) void hist_kernel(
    const int* __restrict__ ei_pt, const int* __restrict__ ei_tt,
    const int* __restrict__ ei_tp, const int* __restrict__ ei_pp,
    int* __restrict__ counts)
{
    const int rel = blockIdx.y;
    const int* ei = (rel == 0) ? ei_pt : (rel == 1) ? ei_tt : (rel == 2) ? ei_tp : ei_pp;
    int* cnt = counts + (size_t)rel * NN;
    const int stride = gridDim.x * 256;
    for (int e = blockIdx.x * 256 + threadIdx.x; e < NE; e += stride)
        atomicAdd(&cnt[ei[NE + e]], 1);
}

// ---------------- scan P1: per-chunk (1024 ints) partial sums ----------------
__global__ __launch_bounds__(256) void scan_part1(
    const int* __restrict__ counts, int* __restrict__ bsum)
{
    const int rel = blockIdx.y;
    const int b = blockIdx.x;
    const int idx = b * 1024 + threadIdx.x * 4;
    const int* cnt = counts + (size_t)rel * NN;
    int s = 0;
    if (idx < NN) { int4 c = *(const int4*)(cnt + idx); s = c.x + c.y + c.z + c.w; }
#pragma unroll
    for (int off = 1; off < 64; off <<= 1) s += __shfl_xor(s, off);
    __shared__ int ws[4];
    if ((threadIdx.x & 63) == 0) ws[threadIdx.x >> 6] = s;
    __syncthreads();
    if (threadIdx.x == 0) bsum[rel * CHB + b] = ws[0] + ws[1] + ws[2] + ws[3];
}

// ---------------- scan P2: exclusive-scan the 98 block sums (per rel), in place ----------------
__global__ __launch_bounds__(128) void scan_part2(int* __restrict__ bsum, int* __restrict__ offs)
{
    const int rel = blockIdx.x;
    int* bs = bsum + rel * CHB;
    __shared__ int sm[128];
    const int tid = threadIdx.x;
    int v = (tid < CHB) ? bs[tid] : 0;
    sm[tid] = v;
    __syncthreads();
    for (int off = 1; off < 128; off <<= 1) {
        int t = (tid >= off) ? sm[tid - off] : 0;
        __syncthreads();
        sm[tid] += t;
        __syncthreads();
    }
    if (tid < CHB) bs[tid] = sm[tid] - v;   // exclusive
    if (tid == 0) offs[(size_t)rel * (NN + 1) + NN] = NE;
}

// ---------------- scan P3: block-local exclusive scan + base; writes offs & cursor ----------------
__global__ __launch_bounds__(256) void scan_part3(
    const int* __restrict__ counts, const int* __restrict__ bsum,
    int* __restrict__ offs, int* __restrict__ cursor)
{
    const int rel = blockIdx.y;
    const int b = blockIdx.x;
    const int idx = b * 1024 + threadIdx.x * 4;
    const int* cnt = counts + (size_t)rel * NN;
    int* of = offs + (size_t)rel * (NN + 1);
    int* cu = cursor + (size_t)rel * NN;

    int4 c = make_int4(0, 0, 0, 0);
    if (idx < NN) c = *(const int4*)(cnt + idx);
    const int s = c.x + c.y + c.z + c.w;

    const int lane = threadIdx.x & 63;
    const int wid  = threadIdx.x >> 6;
    int incl = s;
#pragma unroll
    for (int off = 1; off < 64; off <<= 1) {
        int t = __shfl_up(incl, off);
        if (lane >= off) incl += t;
    }
    __shared__ int wsum[4];
    if (lane == 63) wsum[wid] = incl;
    __syncthreads();
    int wbase = 0;
    for (int w = 0; w < wid; ++w) wbase += wsum[w];

    const int base = bsum[rel * CHB + b] + wbase + (incl - s);
    if (idx < NN) {
        const int o0 = base;
        of[idx]     = o0;                   cu[idx]     = o0;
        of[idx + 1] = o0 + c.x;             cu[idx + 1] = o0 + c.x;
        of[idx + 2] = o0 + c.x + c.y;       cu[idx + 2] = o0 + c.x + c.y;
        of[idx + 3] = o0 + c.x + c.y + c.z; cu[idx + 3] = o0 + c.x + c.y + c.z;
    }
}

// ---------------- CSR build: scatter src into dst-bins ----------------
__global__ __launch_bounds__(256) void scatter_kernel(
    const int* __restrict__ ei_pt, const int* __restrict__ ei_tt,
    const int* __restrict__ ei_tp, const int* __restrict__ ei_pp,
    int* __restrict__ cursor, int* __restrict__ perm)
{
    const int rel = blockIdx.y;
    const int* ei = (rel == 0) ? ei_pt : (rel == 1) ? ei_tt : (rel == 2) ? ei_tp : ei_pp;
    int* cu = cursor + (size_t)rel * NN;
    int* pm = perm + (size_t)rel * NE;
    const int stride = gridDim.x * 256;
    for (int e = blockIdx.x * 256 + threadIdx.x; e < NE; e += stride) {
        const int src = ei[e];
        const int dst = ei[NE + e];
        const int pos = atomicAdd(&cu[dst], 1);
        pm[pos] = src;
    }
}

// ---------------- accumulate: wave per dst node; 8-deep uniform-broadcast edge chunks ----------------
// rel 0: pt -> trans r0 ; rel 1: tt -> trans r1 ; rel 2: tp -> place r0 ; rel 3: pp -> place r1
__global__ __launch_bounds__(256) void acc_kernel(
    const u16* __restrict__ hb_place, const u16* __restrict__ hb_trans,
    const float* __restrict__ al_place, const float* __restrict__ al_trans,
    const int* __restrict__ offs, const int* __restrict__ perm,
    const float* __restrict__ kW, const float* __restrict__ kb,
    u16* __restrict__ outb, float* __restrict__ mean_acc)
{
    const int rel = blockIdx.y;
    const u16* hb; const float* als; const float* ald;
    if (rel == 0)      { hb = hb_place; als = al_place + 0 * NN * 4; ald = al_trans + 2 * NN * 4; }
    else if (rel == 1) { hb = hb_trans; als = al_trans + 1 * NN * 4; ald = al_trans + 3 * NN * 4; }
    else if (rel == 2) { hb = hb_trans; als = al_trans + 0 * NN * 4; ald = al_place + 2 * NN * 4; }
    else               { hb = hb_place; als = al_place + 1 * NN * 4; ald = al_place + 3 * NN * 4; }
    const int* of = offs + (size_t)rel * (NN + 1);
    const int* pm = perm + (size_t)rel * NE;
    u16* ob = outb + (size_t)rel * NN * FO;

    __shared__ float kWl[FO * FO];
    for (int i = threadIdx.x; i < FO * FO; i += 256) kWl[i] = kW[i];
    __syncthreads();

    const int lane = threadIdx.x & 63;
    const int wid  = threadIdx.x >> 6;
    const int head = lane >> 4;
    const float kbv = kb[lane];

    float ts = 0.f;
    const int gw = blockIdx.x * 4 + wid;
    const int nw = gridDim.x * 4;
    for (int n = gw; n < NN; n += nw) {
        const int beg = of[n], end = of[n + 1];
        const float advh = ald[n * 4 + head];    // this lane's head component
        float num = 0.f, den = 0.f;

        for (int c = beg; c < end; c += 8) {
            // load up to 8 src indices (uniform broadcast loads, addresses known now)
            int s[8];
#pragma unroll
            for (int j = 0; j < 8; ++j)
                s[j] = (c + j < end) ? pm[c + j] : 0;
            // 8 independent logit gathers + exp (per-lane = its head's value)
            float ee[8];
#pragma unroll
            for (int j = 0; j < 8; ++j) {
                float a = als[s[j] * 4 + head] + advh;
                a = a > 0.f ? a : 0.2f * a;
                float e = __expf(a);
                ee[j] = (c + j < end) ? e : 0.f;
            }
            // 8 independent 128B h-row gathers; every lane accumulates den directly
#pragma unroll
            for (int j = 0; j < 8; ++j) {
                const float hv = bf2f(hb[(size_t)s[j] * FO + lane]);
                num = fmaf(hv, ee[j], num);
                den += ee[j];
            }
        }

        const float outv = fmaxf(num / (den + 1e-16f), 0.f);
        ob[(size_t)n * FO + lane] = f2bf(outv);

        // fused semantic-attention partial: y = out_row @ kW + kb, ts += tanh(y)
        float y = kbv;
#pragma unroll
        for (int k = 0; k < 64; ++k) y = fmaf(__shfl(outv, k), kWl[k * FO + lane], y);
        ts += tanhf(y);
    }

    __shared__ float red[4][64];
    red[wid][lane] = ts;
    __syncthreads();
    if (wid == 0) {
        const float sum = red[0][lane] + red[1][lane] + red[2][lane] + red[3][lane];
        unsafeAtomicAdd(&mean_acc[rel * 64 + lane], sum);
    }
}

// ---------------- score: semantic attention weights ----------------
__global__ void score_kernel(const float* __restrict__ mean_acc, const float* __restrict__ q,
                             float* __restrict__ attn)
{
    const int lane = threadIdx.x;  // 64 threads
    const float qv = q[lane];
    float sc[4];
#pragma unroll
    for (int r = 0; r < 4; ++r) {
        float p = qv * mean_acc[r * 64 + lane] * (1.0f / (float)NN);
#pragma unroll
        for (int off = 1; off < 64; off <<= 1) p += __shfl_xor(p, off);
        sc[r] = p;
    }
    if (lane == 0) {
        float m = fmaxf(sc[0], sc[1]);
        float e0 = expf(sc[0] - m), e1 = expf(sc[1] - m);
        attn[0] = e0 / (e0 + e1);
        attn[1] = e1 / (e0 + e1);
        m = fmaxf(sc[2], sc[3]);
        float f0 = expf(sc[2] - m), f1 = expf(sc[3] - m);
        attn[2] = f0 / (f0 + f1);
        attn[3] = f1 / (f0 + f1);
    }
}

// ---------------- combine: out = attn0*out_r0 + attn1*out_r1 (float32 output) ----------------
__global__ __launch_bounds__(256) void combine_kernel(
    const u16* __restrict__ outb, const float* __restrict__ attn, float* __restrict__ out)
{
    const int type = blockIdx.y;           // 0 = place (rels 2,3), 1 = trans (rels 0,1)
    const int r0 = (type == 0) ? 2 : 0;
    const float a0 = attn[r0], a1 = attn[r0 + 1];
    const ushort4* o0 = (const ushort4*)(outb + (size_t)r0 * NN * FO);
    const ushort4* o1 = (const ushort4*)(outb + (size_t)(r0 + 1) * NN * FO);
    float4* dst = (float4*)(out + (size_t)type * NN * FO);
    const int n4 = NN * FO / 4;
    const int stride = gridDim.x * 256;
    for (int i = blockIdx.x * 256 + threadIdx.x; i < n4; i += stride) {
        const ushort4 u = o0[i];
        const ushort4 w = o1[i];
        float4 r;
        r.x = a0 * bf2f(u.x) + a1 * bf2f(w.x);
        r.y = a0 * bf2f(u.y) + a1 * bf2f(w.y);
        r.z = a0 * bf2f(u.z) + a1 * bf2f(w.z);
        r.w = a0 * bf2f(u.w) + a1 * bf2f(w.w);
        dst[i] = r;
    }
}

extern "C" void kernel_launch(void* const* d_in, const int* in_sizes, int n_in,
                              void* d_out, int out_size, void* d_ws, size_t ws_size,
                              hipStream_t stream)
{
    const float* x_place = (const float*)d_in[0];
    const float* x_trans = (const float*)d_in[1];
    const float* W_place = (const float*)d_in[2];
    const float* b_place = (const float*)d_in[3];
    const float* W_trans = (const float*)d_in[4];
    const float* b_trans = (const float*)d_in[5];
    const float* as_pt = (const float*)d_in[6];
    const float* ad_pt = (const float*)d_in[7];
    const float* as_tp = (const float*)d_in[8];
    const float* ad_tp = (const float*)d_in[9];
    const float* as_pp = (const float*)d_in[10];
    const float* ad_pp = (const float*)d_in[11];
    const float* as_tt = (const float*)d_in[12];
    const float* ad_tt = (const float*)d_in[13];
    const float* q  = (const float*)d_in[14];
    const float* kW = (const float*)d_in[15];
    const float* kb = (const float*)d_in[16];
    const int* ei_pt = (const int*)d_in[17];
    const int* ei_tp = (const int*)d_in[18];
    const int* ei_pp = (const int*)d_in[19];
    const int* ei_tt = (const int*)d_in[20];

    // ---- workspace layout ----
    char* ws = (char*)d_ws;
    u16* hb_place = (u16*)ws;                                     // NN*64 bf16 = 12.8 MB
    u16* hb_trans = hb_place + (size_t)NN * FO;                   // 12.8 MB
    float* al_place = (float*)(hb_trans + (size_t)NN * FO);       // 4*NN*4 f32 = 6.4 MB
    float* al_trans = al_place + 4 * (size_t)NN * 4;              // 6.4 MB
    u16* outb = (u16*)(al_trans + 4 * (size_t)NN * 4);            // 4*NN*64 bf16 = 51.2 MB
    int* counts = (int*)(outb + 4 * (size_t)NN * FO);             // 4*NN int = 1.6 MB
    float* mean_acc = (float*)(counts + 4 * (size_t)NN);          // 256 f32
    float* attn = mean_acc + 256;                                 // 4 f32
    int* offs = (int*)(attn + 4);                                 // 4*(NN+1) int
    int* cursor = offs + 4 * (size_t)(NN + 1);                    // 4*NN int
    int* perm = cursor + 4 * (size_t)NN;                          // 4*NE int = 16 MB
    int* bsum = perm + 4 * (size_t)NE;                            // 4*CHB int

    // zero counts + mean_acc (+attn) in one shot
    hipMemsetAsync(counts, 0, (4 * (size_t)NN + 256 + 4) * sizeof(int), stream);

    // place node roles: src of pt, src of pp, dst of tp, dst of pp
    proj_kernel<<<2048, 256, 0, stream>>>(x_place, W_place, b_place,
                                          as_pt, as_pp, ad_tp, ad_pp,
                                          hb_place, al_place);
    // trans node roles: src of tp, src of tt, dst of pt, dst of tt
    proj_kernel<<<2048, 256, 0, stream>>>(x_trans, W_trans, b_trans,
                                          as_tp, as_tt, ad_pt, ad_tt,
                                          hb_trans, al_trans);

    hist_kernel<<<dim3(2048, 4), 256, 0, stream>>>(ei_pt, ei_tt, ei_tp, ei_pp, counts);
    scan_part1<<<dim3(CHB, 4), 256, 0, stream>>>(counts, bsum);
    scan_part2<<<4, 128, 0, stream>>>(bsum, offs);
    scan_part3<<<dim3(CHB, 4), 256, 0, stream>>>(counts, bsum, offs, cursor);
    scatter_kernel<<<dim3(2048, 4), 256, 0, stream>>>(ei_pt, ei_tt, ei_tp, ei_pp, cursor, perm);

    acc_kernel<<<dim3(2048, 4), 256, 0, stream>>>(hb_place, hb_trans, al_place, al_trans,
                                                  offs, perm, kW, kb, outb, mean_acc);

    score_kernel<<<1, 64, 0, stream>>>(mean_acc, q, attn);

    combine_kernel<<<dim3(1024, 2), 256, 0, stream>>>(outb, attn, (float*)d_out);
}

// Round 7
// 993.319 us; speedup vs baseline: 2.0323x; 2.0323x over previous
//
#include <hip/hip_runtime.h>
#include <hip/hip_bf16.h>

#define NN 100000        // nodes per type
#define NE 1000000       // edges per relation
#define FI 128
#define FO 64
#define CHB 98           // ceil(NN/1024) scan chunks

typedef unsigned short u16;
typedef unsigned int u32;

__device__ __forceinline__ float bf2f(u16 u) {
    return __uint_as_float(((u32)u) << 16);
}
__device__ __forceinline__ u16 f2bf(float f) {
    __hip_bfloat16 h = __float2bfloat16(f);
    return *(u16*)&h;
}

// ---------------- projection + attention-logit kernel ----------------
// Wave per node. x[n][k] is wave-uniform -> scalar loads; W column from LDS (2-way=free).
__global__ __launch_bounds__(256) void proj_kernel(
    const float* __restrict__ x, const float* __restrict__ W, const float* __restrict__ b,
    const float* __restrict__ a0, const float* __restrict__ a1,
    const float* __restrict__ a2, const float* __restrict__ a3,
    u16* __restrict__ hout, float* __restrict__ al)
{
    __shared__ float Wl[FI * FO];
    for (int i = threadIdx.x; i < FI * FO; i += 256) Wl[i] = W[i];
    __syncthreads();

    const int lane = threadIdx.x & 63;
    const int wid  = threadIdx.x >> 6;
    const int gw   = blockIdx.x * 4 + wid;
    const int nw   = gridDim.x * 4;
    const int head = lane >> 4;

    const float bv  = b[lane];
    const float av0 = a0[lane];
    const float av1 = a1[lane];
    const float av2 = a2[lane];
    const float av3 = a3[lane];

    for (int n = gw; n < NN; n += nw) {
        const int nu = __builtin_amdgcn_readfirstlane(n);
        const float* __restrict__ xr = x + (size_t)nu * FI;
        float acc = bv;
#pragma unroll
        for (int k = 0; k < FI; ++k)
            acc = fmaf(xr[k], Wl[k * FO + lane], acc);   // sgpr * lds -> fma

        hout[(size_t)nu * FO + lane] = f2bf(acc);

        float p0 = acc * av0, p1 = acc * av1, p2 = acc * av2, p3 = acc * av3;
#pragma unroll
        for (int off = 1; off < 16; off <<= 1) {
            p0 += __shfl_xor(p0, off);
            p1 += __shfl_xor(p1, off);
            p2 += __shfl_xor(p2, off);
            p3 += __shfl_xor(p3, off);
        }
        if ((lane & 15) == 0) {
            al[0 * NN * 4 + nu * 4 + head] = p0;
            al[1 * NN * 4 + nu * 4 + head] = p1;
            al[2 * NN * 4 + nu * 4 + head] = p2;
            al[3 * NN * 4 + nu * 4 + head] = p3;
        }
    }
}

// ---------------- CSR build: histogram ----------------
__global__ __launch_bounds__(256) void hist_kernel(
    const int* __restrict__ ei_pt, const int* __restrict__ ei_tt,
    const int* __restrict__ ei_tp, const int* __restrict__ ei_pp,
    int* __restrict__ counts)
{
    const int rel = blockIdx.y;
    const int* ei = (rel == 0) ? ei_pt : (rel == 1) ? ei_tt : (rel == 2) ? ei_tp : ei_pp;
    int* cnt = counts + (size_t)rel * NN;
    const int stride = gridDim.x * 256;
    for (int e = blockIdx.x * 256 + threadIdx.x; e < NE; e += stride)
        atomicAdd(&cnt[ei[NE + e]], 1);
}

// ---------------- scan P1: per-chunk (1024 ints) partial sums ----------------
__global__ __launch_bounds__(256) void scan_part1(
    const int* __restrict__ counts, int* __restrict__ bsum)
{
    const int rel = blockIdx.y;
    const int b = blockIdx.x;
    const int idx = b * 1024 + threadIdx.x * 4;
    const int* cnt = counts + (size_t)rel * NN;
    int s = 0;
    if (idx < NN) { int4 c = *(const int4*)(cnt + idx); s = c.x + c.y + c.z + c.w; }
#pragma unroll
    for (int off = 1; off < 64; off <<= 1) s += __shfl_xor(s, off);
    __shared__ int ws[4];
    if ((threadIdx.x & 63) == 0) ws[threadIdx.x >> 6] = s;
    __syncthreads();
    if (threadIdx.x == 0) bsum[rel * CHB + b] = ws[0] + ws[1] + ws[2] + ws[3];
}

// ---------------- scan P2: exclusive-scan the 98 block sums (per rel), in place ----------------
__global__ __launch_bounds__(128) void scan_part2(int* __restrict__ bsum, int* __restrict__ offs)
{
    const int rel = blockIdx.x;
    int* bs = bsum + rel * CHB;
    __shared__ int sm[128];
    const int tid = threadIdx.x;
    int v = (tid < CHB) ? bs[tid] : 0;
    sm[tid] = v;
    __syncthreads();
    for (int off = 1; off < 128; off <<= 1) {
        int t = (tid >= off) ? sm[tid - off] : 0;
        __syncthreads();
        sm[tid] += t;
        __syncthreads();
    }
    if (tid < CHB) bs[tid] = sm[tid] - v;   // exclusive
    if (tid == 0) offs[(size_t)rel * (NN + 1) + NN] = NE;
}

// ---------------- scan P3: block-local exclusive scan + base; writes offs & cursor ----------------
__global__ __launch_bounds__(256) void scan_part3(
    const int* __restrict__ counts, const int* __restrict__ bsum,
    int* __restrict__ offs, int* __restrict__ cursor)
{
    const int rel = blockIdx.y;
    const int b = blockIdx.x;
    const int idx = b * 1024 + threadIdx.x * 4;
    const int* cnt = counts + (size_t)rel * NN;
    int* of = offs + (size_t)rel * (NN + 1);
    int* cu = cursor + (size_t)rel * NN;

    int4 c = make_int4(0, 0, 0, 0);
    if (idx < NN) c = *(const int4*)(cnt + idx);
    const int s = c.x + c.y + c.z + c.w;

    const int lane = threadIdx.x & 63;
    const int wid  = threadIdx.x >> 6;
    int incl = s;
#pragma unroll
    for (int off = 1; off < 64; off <<= 1) {
        int t = __shfl_up(incl, off);
        if (lane >= off) incl += t;
    }
    __shared__ int wsum[4];
    if (lane == 63) wsum[wid] = incl;
    __syncthreads();
    int wbase = 0;
    for (int w = 0; w < wid; ++w) wbase += wsum[w];

    const int base = bsum[rel * CHB + b] + wbase + (incl - s);
    if (idx < NN) {
        const int o0 = base;
        of[idx]     = o0;                   cu[idx]     = o0;
        of[idx + 1] = o0 + c.x;             cu[idx + 1] = o0 + c.x;
        of[idx + 2] = o0 + c.x + c.y;       cu[idx + 2] = o0 + c.x + c.y;
        of[idx + 3] = o0 + c.x + c.y + c.z; cu[idx + 3] = o0 + c.x + c.y + c.z;
    }
}

// ---------------- CSR build: scatter src into dst-bins ----------------
__global__ __launch_bounds__(256) void scatter_kernel(
    const int* __restrict__ ei_pt, const int* __restrict__ ei_tt,
    const int* __restrict__ ei_tp, const int* __restrict__ ei_pp,
    int* __restrict__ cursor, int* __restrict__ perm)
{
    const int rel = blockIdx.y;
    const int* ei = (rel == 0) ? ei_pt : (rel == 1) ? ei_tt : (rel == 2) ? ei_tp : ei_pp;
    int* cu = cursor + (size_t)rel * NN;
    int* pm = perm + (size_t)rel * NE;
    const int stride = gridDim.x * 256;
    for (int e = blockIdx.x * 256 + threadIdx.x; e < NE; e += stride) {
        const int src = ei[e];
        const int dst = ei[NE + e];
        const int pos = atomicAdd(&cu[dst], 1);
        pm[pos] = src;
    }
}

// ---------------- accumulate: wave per dst node; scalar-pipe indices/logits, vector hb gather ----------------
// rel 0: pt -> trans r0 ; rel 1: tt -> trans r1 ; rel 2: tp -> place r0 ; rel 3: pp -> place r1
__global__ __launch_bounds__(256) void acc_kernel(
    const u16* __restrict__ hb_place, const u16* __restrict__ hb_trans,
    const float* __restrict__ al_place, const float* __restrict__ al_trans,
    const int* __restrict__ offs, const int* __restrict__ perm,
    u16* __restrict__ outb)
{
    const int rel = blockIdx.y;
    const u16* hb; const float* als; const float* ald;
    if (rel == 0)      { hb = hb_place; als = al_place + 0 * NN * 4; ald = al_trans + 2 * NN * 4; }
    else if (rel == 1) { hb = hb_trans; als = al_trans + 1 * NN * 4; ald = al_trans + 3 * NN * 4; }
    else if (rel == 2) { hb = hb_trans; als = al_trans + 0 * NN * 4; ald = al_place + 2 * NN * 4; }
    else               { hb = hb_place; als = al_place + 1 * NN * 4; ald = al_place + 3 * NN * 4; }
    const int* of = offs + (size_t)rel * (NN + 1);
    const int* pm = perm + (size_t)rel * NE;
    u16* ob = outb + (size_t)rel * NN * FO;

    const int lane = threadIdx.x & 63;
    const int wid  = threadIdx.x >> 6;
    const int head = lane >> 4;

    const int gw = blockIdx.x * 4 + wid;
    const int nw = gridDim.x * 4;
    for (int n = gw; n < NN; n += nw) {
        const int nu = __builtin_amdgcn_readfirstlane(n);
        const int beg = of[nu], end = of[nu + 1];         // s_loads
        const float advh = ald[nu * 4 + head];
        float num = 0.f, den = 0.f;

        int c = beg;
        for (; c + 4 <= end; c += 4) {
            const int s0 = pm[c], s1 = pm[c + 1], s2 = pm[c + 2], s3 = pm[c + 3]; // s_loads
            const float4 v0 = *(const float4*)(als + (size_t)s0 * 4);  // s_load_x4
            const float4 v1 = *(const float4*)(als + (size_t)s1 * 4);
            const float4 v2 = *(const float4*)(als + (size_t)s2 * 4);
            const float4 v3 = *(const float4*)(als + (size_t)s3 * 4);
            float a0 = ((head == 0) ? v0.x : (head == 1) ? v0.y : (head == 2) ? v0.z : v0.w) + advh;
            float a1 = ((head == 0) ? v1.x : (head == 1) ? v1.y : (head == 2) ? v1.z : v1.w) + advh;
            float a2 = ((head == 0) ? v2.x : (head == 1) ? v2.y : (head == 2) ? v2.z : v2.w) + advh;
            float a3 = ((head == 0) ? v3.x : (head == 1) ? v3.y : (head == 2) ? v3.z : v3.w) + advh;
            a0 = a0 > 0.f ? a0 : 0.2f * a0;
            a1 = a1 > 0.f ? a1 : 0.2f * a1;
            a2 = a2 > 0.f ? a2 : 0.2f * a2;
            a3 = a3 > 0.f ? a3 : 0.2f * a3;
            const float e0 = __expf(a0), e1 = __expf(a1), e2 = __expf(a2), e3 = __expf(a3);
            const float h0 = bf2f(hb[(size_t)s0 * FO + lane]);
            const float h1 = bf2f(hb[(size_t)s1 * FO + lane]);
            const float h2 = bf2f(hb[(size_t)s2 * FO + lane]);
            const float h3 = bf2f(hb[(size_t)s3 * FO + lane]);
            num = fmaf(h0, e0, num);
            num = fmaf(h1, e1, num);
            num = fmaf(h2, e2, num);
            num = fmaf(h3, e3, num);
            den += (e0 + e1) + (e2 + e3);
        }
        for (; c < end; ++c) {
            const int s0 = pm[c];
            const float4 v0 = *(const float4*)(als + (size_t)s0 * 4);
            float a0 = ((head == 0) ? v0.x : (head == 1) ? v0.y : (head == 2) ? v0.z : v0.w) + advh;
            a0 = a0 > 0.f ? a0 : 0.2f * a0;
            const float e0 = __expf(a0);
            const float h0 = bf2f(hb[(size_t)s0 * FO + lane]);
            num = fmaf(h0, e0, num);
            den += e0;
        }

        const float outv = fmaxf(num / (den + 1e-16f), 0.f);
        ob[(size_t)nu * FO + lane] = f2bf(outv);
    }
}

// ---------------- semantic: ts[f] += tanh(out_row @ kW + kb)[f], kW column in VGPRs ----------------
__global__ __launch_bounds__(256) void sem_kernel(
    const u16* __restrict__ outb, const float* __restrict__ kW, const float* __restrict__ kb,
    float* __restrict__ mean_acc)
{
    const int rel = blockIdx.y;
    const u16* ob = outb + (size_t)rel * NN * FO;

    const int lane = threadIdx.x & 63;
    const int wid  = threadIdx.x >> 6;

    float kwc[FO];
#pragma unroll
    for (int k = 0; k < FO; ++k) kwc[k] = kW[k * FO + lane];
    const float kbv = kb[lane];

    float ts = 0.f;
    const int gw = blockIdx.x * 4 + wid;
    const int nw = gridDim.x * 4;
    for (int n = gw; n < NN; n += nw) {
        const int nu = __builtin_amdgcn_readfirstlane(n);
        const u32* rw = (const u32*)(ob + (size_t)nu * FO);   // 32 uniform words -> s_loads
        float y = kbv;
#pragma unroll
        for (int i = 0; i < 32; ++i) {
            const u32 w = rw[i];
            y = fmaf(__uint_as_float(w << 16),          kwc[2 * i],     y);  // elem 2i (low half)
            y = fmaf(__uint_as_float(w & 0xffff0000u),  kwc[2 * i + 1], y);  // elem 2i+1
        }
        ts += tanhf(y);
    }

    __shared__ float red[4][64];
    red[wid][lane] = ts;
    __syncthreads();
    if (wid == 0) {
        const float sum = red[0][lane] + red[1][lane] + red[2][lane] + red[3][lane];
        unsafeAtomicAdd(&mean_acc[rel * 64 + lane], sum);
    }
}

// ---------------- score: semantic attention weights ----------------
__global__ void score_kernel(const float* __restrict__ mean_acc, const float* __restrict__ q,
                             float* __restrict__ attn)
{
    const int lane = threadIdx.x;  // 64 threads
    const float qv = q[lane];
    float sc[4];
#pragma unroll
    for (int r = 0; r < 4; ++r) {
        float p = qv * mean_acc[r * 64 + lane] * (1.0f / (float)NN);
#pragma unroll
        for (int off = 1; off < 64; off <<= 1) p += __shfl_xor(p, off);
        sc[r] = p;
    }
    if (lane == 0) {
        float m = fmaxf(sc[0], sc[1]);
        float e0 = expf(sc[0] - m), e1 = expf(sc[1] - m);
        attn[0] = e0 / (e0 + e1);
        attn[1] = e1 / (e0 + e1);
        m = fmaxf(sc[2], sc[3]);
        float f0 = expf(sc[2] - m), f1 = expf(sc[3] - m);
        attn[2] = f0 / (f0 + f1);
        attn[3] = f1 / (f0 + f1);
    }
}

// ---------------- combine: out = attn0*out_r0 + attn1*out_r1 (float32 output) ----------------
__global__ __launch_bounds__(256) void combine_kernel(
    const u16* __restrict__ outb, const float* __restrict__ attn, float* __restrict__ out)
{
    const int type = blockIdx.y;           // 0 = place (rels 2,3), 1 = trans (rels 0,1)
    const int r0 = (type == 0) ? 2 : 0;
    const float a0 = attn[r0], a1 = attn[r0 + 1];
    const ushort4* o0 = (const ushort4*)(outb + (size_t)r0 * NN * FO);
    const ushort4* o1 = (const ushort4*)(outb + (size_t)(r0 + 1) * NN * FO);
    float4* dst = (float4*)(out + (size_t)type * NN * FO);
    const int n4 = NN * FO / 4;
    const int stride = gridDim.x * 256;
    for (int i = blockIdx.x * 256 + threadIdx.x; i < n4; i += stride) {
        const ushort4 u = o0[i];
        const ushort4 w = o1[i];
        float4 r;
        r.x = a0 * bf2f(u.x) + a1 * bf2f(w.x);
        r.y = a0 * bf2f(u.y) + a1 * bf2f(w.y);
        r.z = a0 * bf2f(u.z) + a1 * bf2f(w.z);
        r.w = a0 * bf2f(u.w) + a1 * bf2f(w.w);
        dst[i] = r;
    }
}

extern "C" void kernel_launch(void* const* d_in, const int* in_sizes, int n_in,
                              void* d_out, int out_size, void* d_ws, size_t ws_size,
                              hipStream_t stream)
{
    const float* x_place = (const float*)d_in[0];
    const float* x_trans = (const float*)d_in[1];
    const float* W_place = (const float*)d_in[2];
    const float* b_place = (const float*)d_in[3];
    const float* W_trans = (const float*)d_in[4];
    const float* b_trans = (const float*)d_in[5];
    const float* as_pt = (const float*)d_in[6];
    const float* ad_pt = (const float*)d_in[7];
    const float* as_tp = (const float*)d_in[8];
    const float* ad_tp = (const float*)d_in[9];
    const float* as_pp = (const float*)d_in[10];
    const float* ad_pp = (const float*)d_in[11];
    const float* as_tt = (const float*)d_in[12];
    const float* ad_tt = (const float*)d_in[13];
    const float* q  = (const float*)d_in[14];
    const float* kW = (const float*)d_in[15];
    const float* kb = (const float*)d_in[16];
    const int* ei_pt = (const int*)d_in[17];
    const int* ei_tp = (const int*)d_in[18];
    const int* ei_pp = (const int*)d_in[19];
    const int* ei_tt = (const int*)d_in[20];

    // ---- workspace layout ----
    char* ws = (char*)d_ws;
    u16* hb_place = (u16*)ws;                                     // NN*64 bf16 = 12.8 MB
    u16* hb_trans = hb_place + (size_t)NN * FO;                   // 12.8 MB
    float* al_place = (float*)(hb_trans + (size_t)NN * FO);       // 4*NN*4 f32 = 6.4 MB
    float* al_trans = al_place + 4 * (size_t)NN * 4;              // 6.4 MB
    u16* outb = (u16*)(al_trans + 4 * (size_t)NN * 4);            // 4*NN*64 bf16 = 51.2 MB
    int* counts = (int*)(outb + 4 * (size_t)NN * FO);             // 4*NN int = 1.6 MB
    float* mean_acc = (float*)(counts + 4 * (size_t)NN);          // 256 f32
    float* attn = mean_acc + 256;                                 // 4 f32
    int* offs = (int*)(attn + 4);                                 // 4*(NN+1) int
    int* cursor = offs + 4 * (size_t)(NN + 1);                    // 4*NN int
    int* perm = cursor + 4 * (size_t)NN;                          // 4*NE int = 16 MB
    int* bsum = perm + 4 * (size_t)NE;                            // 4*CHB int

    // zero counts + mean_acc (+attn) in one shot
    hipMemsetAsync(counts, 0, (4 * (size_t)NN + 256 + 4) * sizeof(int), stream);

    // place node roles: src of pt, src of pp, dst of tp, dst of pp
    proj_kernel<<<1024, 256, 0, stream>>>(x_place, W_place, b_place,
                                          as_pt, as_pp, ad_tp, ad_pp,
                                          hb_place, al_place);
    // trans node roles: src of tp, src of tt, dst of pt, dst of tt
    proj_kernel<<<1024, 256, 0, stream>>>(x_trans, W_trans, b_trans,
                                          as_tp, as_tt, ad_pt, ad_tt,
                                          hb_trans, al_trans);

    hist_kernel<<<dim3(2048, 4), 256, 0, stream>>>(ei_pt, ei_tt, ei_tp, ei_pp, counts);
    scan_part1<<<dim3(CHB, 4), 256, 0, stream>>>(counts, bsum);
    scan_part2<<<4, 128, 0, stream>>>(bsum, offs);
    scan_part3<<<dim3(CHB, 4), 256, 0, stream>>>(counts, bsum, offs, cursor);
    scatter_kernel<<<dim3(2048, 4), 256, 0, stream>>>(ei_pt, ei_tt, ei_tp, ei_pp, cursor, perm);

    acc_kernel<<<dim3(1024, 4), 256, 0, stream>>>(hb_place, hb_trans, al_place, al_trans,
                                                  offs, perm, outb);

    sem_kernel<<<dim3(512, 4), 256, 0, stream>>>(outb, kW, kb, mean_acc);

    score_kernel<<<1, 64, 0, stream>>>(mean_acc, q, attn);

    combine_kernel<<<dim3(1024, 2), 256, 0, stream>>>(outb, attn, (float*)d_out);
}

// Round 9
// 666.248 us; speedup vs baseline: 3.0300x; 1.4909x over previous
//
#include <hip/hip_runtime.h>
#include <hip/hip_bf16.h>

#define NN 100000        // nodes per type
#define NE 1000000       // edges per relation
#define FI 128
#define FO 64
#define NB 196           // ceil(NN/512) coarse buckets
#define TILE 8192        // edges per csr_place tile

typedef unsigned short u16;
typedef unsigned int u32;

__device__ __forceinline__ float bf2f(u16 u) {
    return __uint_as_float(((u32)u) << 16);
}
__device__ __forceinline__ u16 f2bf(float f) {
    __hip_bfloat16 h = __float2bfloat16(f);
    return *(u16*)&h;
}

// ---------------- projection + attention-logit kernel ----------------
// Wave per node. x[n][k] is wave-uniform -> scalar loads; W column from LDS.
__global__ __launch_bounds__(256) void proj_kernel(
    const float* __restrict__ x, const float* __restrict__ W, const float* __restrict__ b,
    const float* __restrict__ a0, const float* __restrict__ a1,
    const float* __restrict__ a2, const float* __restrict__ a3,
    u16* __restrict__ hout, float* __restrict__ al)
{
    __shared__ float Wl[FI * FO];
    for (int i = threadIdx.x; i < FI * FO; i += 256) Wl[i] = W[i];
    __syncthreads();

    const int lane = threadIdx.x & 63;
    const int wid  = threadIdx.x >> 6;
    const int gw   = blockIdx.x * 4 + wid;
    const int nw   = gridDim.x * 4;
    const int head = lane >> 4;

    const float bv  = b[lane];
    const float av0 = a0[lane];
    const float av1 = a1[lane];
    const float av2 = a2[lane];
    const float av3 = a3[lane];

    for (int n = gw; n < NN; n += nw) {
        const int nu = __builtin_amdgcn_readfirstlane(n);
        const float* __restrict__ xr = x + (size_t)nu * FI;
        float acc = bv;
#pragma unroll
        for (int k = 0; k < FI; ++k)
            acc = fmaf(xr[k], Wl[k * FO + lane], acc);   // sgpr * lds -> fma

        hout[(size_t)nu * FO + lane] = f2bf(acc);

        float p0 = acc * av0, p1 = acc * av1, p2 = acc * av2, p3 = acc * av3;
#pragma unroll
        for (int off = 1; off < 16; off <<= 1) {
            p0 += __shfl_xor(p0, off);
            p1 += __shfl_xor(p1, off);
            p2 += __shfl_xor(p2, off);
            p3 += __shfl_xor(p3, off);
        }
        if ((lane & 15) == 0) {
            al[0 * NN * 4 + nu * 4 + head] = p0;
            al[1 * NN * 4 + nu * 4 + head] = p1;
            al[2 * NN * 4 + nu * 4 + head] = p2;
            al[3 * NN * 4 + nu * 4 + head] = p3;
        }
    }
}

// ---------------- CSR A0: coarse bucket histogram (256 buckets = dst>>9) ----------------
__global__ __launch_bounds__(256) void csr_count(
    const int* __restrict__ ei_pt, const int* __restrict__ ei_tt,
    const int* __restrict__ ei_tp, const int* __restrict__ ei_pp,
    int* __restrict__ bucket_hist)
{
    const int rel = blockIdx.y;
    const int* ei = (rel == 0) ? ei_pt : (rel == 1) ? ei_tt : (rel == 2) ? ei_tp : ei_pp;
    __shared__ int lh[256];
    lh[threadIdx.x] = 0;
    __syncthreads();
    const int stride = gridDim.x * 256;
    for (int e = blockIdx.x * 256 + threadIdx.x; e < NE; e += stride)
        atomicAdd(&lh[ei[NE + e] >> 9], 1);
    __syncthreads();
    if (lh[threadIdx.x]) atomicAdd(&bucket_hist[rel * 256 + threadIdx.x], lh[threadIdx.x]);
}

// ---------------- CSR A1: scan 256 bucket counts -> bases + cursors ----------------
__global__ __launch_bounds__(256) void csr_base(
    const int* __restrict__ bucket_hist, int* __restrict__ bstart,
    int* __restrict__ bcursor, int* __restrict__ offs)
{
    const int rel = blockIdx.x;
    const int tid = threadIdx.x;
    __shared__ int sm[256];
    const int v = bucket_hist[rel * 256 + tid];
    sm[tid] = v;
    __syncthreads();
    for (int off = 1; off < 256; off <<= 1) {
        int t = (tid >= off) ? sm[tid - off] : 0;
        __syncthreads();
        sm[tid] += t;
        __syncthreads();
    }
    const int excl = sm[tid] - v;
    bstart[rel * 257 + tid] = excl;
    bcursor[rel * 256 + tid] = excl;
    if (tid == 255) bstart[rel * 257 + 256] = excl + v;   // == NE
    if (tid == 0) offs[(size_t)rel * (NN + 1) + NN] = NE;
}

// ---------------- CSR A2: place edges into bucket-contiguous packed array ----------------
// packed entry: (dst&511)<<17 | src   (src < 2^17)
__global__ __launch_bounds__(256) void csr_place(
    const int* __restrict__ ei_pt, const int* __restrict__ ei_tt,
    const int* __restrict__ ei_tp, const int* __restrict__ ei_pp,
    int* __restrict__ bcursor, u32* __restrict__ packed)
{
    const int rel = blockIdx.y;
    const int* ei = (rel == 0) ? ei_pt : (rel == 1) ? ei_tt : (rel == 2) ? ei_tp : ei_pp;
    u32* pk = packed + (size_t)rel * NE;
    const int tid = threadIdx.x;

    __shared__ int lh[256];   // per-tile bucket hist
    __shared__ int lb[256];   // per-tile bucket cursor (global slots)

    const int ntiles = (NE + TILE - 1) / TILE;
    for (int tile = blockIdx.x; tile < ntiles; tile += gridDim.x) {
        const int t0 = tile * TILE;
        lh[tid] = 0;
        __syncthreads();

        int d[TILE / 256];
#pragma unroll
        for (int i = 0; i < TILE / 256; ++i) {
            const int idx = t0 + i * 256 + tid;
            d[i] = (idx < NE) ? ei[NE + idx] : -1;
            if (d[i] >= 0) atomicAdd(&lh[d[i] >> 9], 1);
        }
        __syncthreads();
        if (lh[tid]) lb[tid] = atomicAdd(&bcursor[rel * 256 + tid], lh[tid]);
        __syncthreads();
#pragma unroll
        for (int i = 0; i < TILE / 256; ++i) {
            const int idx = t0 + i * 256 + tid;
            if (d[i] >= 0) {
                const int src = ei[idx];
                const int slot = atomicAdd(&lb[d[i] >> 9], 1);
                pk[slot] = ((u32)(d[i] & 511) << 17) | (u32)src;
            }
        }
        __syncthreads();
    }
}

// ---------------- CSR B: per-bucket fine sort -> offs + perm ----------------
__global__ __launch_bounds__(256) void csr_build(
    const u32* __restrict__ packed, const int* __restrict__ bstart,
    int* __restrict__ offs, int* __restrict__ perm)
{
    const int rel = blockIdx.y;
    const int b = blockIdx.x;                 // 0..NB-1
    const int tid = threadIdx.x;
    const int base = bstart[rel * 257 + b];
    const int cnt  = bstart[rel * 257 + b + 1] - base;
    const u32* pk = packed + (size_t)rel * NE + base;
    int* of = offs + (size_t)rel * (NN + 1);
    int* pm = perm + (size_t)rel * NE;

    __shared__ int h[512];
    __shared__ int cur[512];
    h[tid] = 0; h[tid + 256] = 0;
    __syncthreads();
    for (int i = tid; i < cnt; i += 256)
        atomicAdd(&h[pk[i] >> 17], 1);
    __syncthreads();
    const int o0 = h[tid], o1 = h[tid + 256];
    for (int off = 1; off < 512; off <<= 1) {
        const int a0 = (tid >= off) ? h[tid - off] : 0;
        const int a1 = (tid + 256 >= off) ? h[tid + 256 - off] : 0;
        __syncthreads();
        h[tid] += a0; h[tid + 256] += a1;
        __syncthreads();
    }
    const int e0 = base + h[tid] - o0;        // global CSR offset for dst b*512+tid
    const int e1 = base + h[tid + 256] - o1;
    const int gd0 = b * 512 + tid;
    const int gd1 = gd0 + 256;
    if (gd0 < NN) of[gd0] = e0;
    if (gd1 < NN) of[gd1] = e1;
    cur[tid] = e0; cur[tid + 256] = e1;
    __syncthreads();
    for (int i = tid; i < cnt; i += 256) {
        const u32 e = pk[i];
        const int slot = atomicAdd(&cur[e >> 17], 1);
        pm[slot] = (int)(e & 0x1FFFFu);
    }
}

// ---------------- accumulate: wave per dst node; scalar-pipe indices/logits, vector hb gather ----------------
// rel 0: pt -> trans r0 ; rel 1: tt -> trans r1 ; rel 2: tp -> place r0 ; rel 3: pp -> place r1
__global__ __launch_bounds__(256) void acc_kernel(
    const u16* __restrict__ hb_place, const u16* __restrict__ hb_trans,
    const float* __restrict__ al_place, const float* __restrict__ al_trans,
    const int* __restrict__ offs, const int* __restrict__ perm,
    u16* __restrict__ outb)
{
    const int rel = blockIdx.y;
    const u16* hb; const float* als; const float* ald;
    if (rel == 0)      { hb = hb_place; als = al_place + 0 * NN * 4; ald = al_trans + 2 * NN * 4; }
    else if (rel == 1) { hb = hb_trans; als = al_trans + 1 * NN * 4; ald = al_trans + 3 * NN * 4; }
    else if (rel == 2) { hb = hb_trans; als = al_trans + 0 * NN * 4; ald = al_place + 2 * NN * 4; }
    else               { hb = hb_place; als = al_place + 1 * NN * 4; ald = al_place + 3 * NN * 4; }
    const int* of = offs + (size_t)rel * (NN + 1);
    const int* pm = perm + (size_t)rel * NE;
    u16* ob = outb + (size_t)rel * NN * FO;

    const int lane = threadIdx.x & 63;
    const int wid  = threadIdx.x >> 6;
    const int head = lane >> 4;

    const int gw = blockIdx.x * 4 + wid;
    const int nw = gridDim.x * 4;
    for (int n = gw; n < NN; n += nw) {
        const int nu = __builtin_amdgcn_readfirstlane(n);
        const int beg = of[nu], end = of[nu + 1];         // s_loads
        const float advh = ald[nu * 4 + head];
        float num = 0.f, den = 0.f;

        int c = beg;
        for (; c + 4 <= end; c += 4) {
            const int s0 = pm[c], s1 = pm[c + 1], s2 = pm[c + 2], s3 = pm[c + 3]; // s_loads
            const float4 v0 = *(const float4*)(als + (size_t)s0 * 4);  // s_load_x4
            const float4 v1 = *(const float4*)(als + (size_t)s1 * 4);
            const float4 v2 = *(const float4*)(als + (size_t)s2 * 4);
            const float4 v3 = *(const float4*)(als + (size_t)s3 * 4);
            float a0 = ((head == 0) ? v0.x : (head == 1) ? v0.y : (head == 2) ? v0.z : v0.w) + advh;
            float a1 = ((head == 0) ? v1.x : (head == 1) ? v1.y : (head == 2) ? v1.z : v1.w) + advh;
            float a2 = ((head == 0) ? v2.x : (head == 1) ? v2.y : (head == 2) ? v2.z : v2.w) + advh;
            float a3 = ((head == 0) ? v3.x : (head == 1) ? v3.y : (head == 2) ? v3.z : v3.w) + advh;
            a0 = a0 > 0.f ? a0 : 0.2f * a0;
            a1 = a1 > 0.f ? a1 : 0.2f * a1;
            a2 = a2 > 0.f ? a2 : 0.2f * a2;
            a3 = a3 > 0.f ? a3 : 0.2f * a3;
            const float e0 = __expf(a0), e1 = __expf(a1), e2 = __expf(a2), e3 = __expf(a3);
            const float h0 = bf2f(hb[(size_t)s0 * FO + lane]);
            const float h1 = bf2f(hb[(size_t)s1 * FO + lane]);
            const float h2 = bf2f(hb[(size_t)s2 * FO + lane]);
            const float h3 = bf2f(hb[(size_t)s3 * FO + lane]);
            num = fmaf(h0, e0, num);
            num = fmaf(h1, e1, num);
            num = fmaf(h2, e2, num);
            num = fmaf(h3, e3, num);
            den += (e0 + e1) + (e2 + e3);
        }
        for (; c < end; ++c) {
            const int s0 = pm[c];
            const float4 v0 = *(const float4*)(als + (size_t)s0 * 4);
            float a0 = ((head == 0) ? v0.x : (head == 1) ? v0.y : (head == 2) ? v0.z : v0.w) + advh;
            a0 = a0 > 0.f ? a0 : 0.2f * a0;
            const float e0 = __expf(a0);
            const float h0 = bf2f(hb[(size_t)s0 * FO + lane]);
            num = fmaf(h0, e0, num);
            den += e0;
        }

        const float outv = fmaxf(num / (den + 1e-16f), 0.f);
        ob[(size_t)nu * FO + lane] = f2bf(outv);
    }
}

// ---------------- semantic: ts[f] += tanh(out_row @ kW + kb)[f], kW column in VGPRs ----------------
__global__ __launch_bounds__(256) void sem_kernel(
    const u16* __restrict__ outb, const float* __restrict__ kW, const float* __restrict__ kb,
    float* __restrict__ mean_acc)
{
    const int rel = blockIdx.y;
    const u16* ob = outb + (size_t)rel * NN * FO;

    const int lane = threadIdx.x & 63;
    const int wid  = threadIdx.x >> 6;

    float kwc[FO];
#pragma unroll
    for (int k = 0; k < FO; ++k) kwc[k] = kW[k * FO + lane];
    const float kbv = kb[lane];

    float ts = 0.f;
    const int gw = blockIdx.x * 4 + wid;
    const int nw = gridDim.x * 4;
    for (int n = gw; n < NN; n += nw) {
        const int nu = __builtin_amdgcn_readfirstlane(n);
        const u32* rw = (const u32*)(ob + (size_t)nu * FO);   // 32 uniform words -> s_loads
        float y = kbv;
#pragma unroll
        for (int i = 0; i < 32; ++i) {
            const u32 w = rw[i];
            y = fmaf(__uint_as_float(w << 16),          kwc[2 * i],     y);  // elem 2i (low half)
            y = fmaf(__uint_as_float(w & 0xffff0000u),  kwc[2 * i + 1], y);  // elem 2i+1
        }
        ts += tanhf(y);
    }

    __shared__ float red[4][64];
    red[wid][lane] = ts;
    __syncthreads();
    if (wid == 0) {
        const float sum = red[0][lane] + red[1][lane] + red[2][lane] + red[3][lane];
        unsafeAtomicAdd(&mean_acc[rel * 64 + lane], sum);
    }
}

// ---------------- score: semantic attention weights ----------------
__global__ void score_kernel(const float* __restrict__ mean_acc, const float* __restrict__ q,
                             float* __restrict__ attn)
{
    const int lane = threadIdx.x;  // 64 threads
    const float qv = q[lane];
    float sc[4];
#pragma unroll
    for (int r = 0; r < 4; ++r) {
        float p = qv * mean_acc[r * 64 + lane] * (1.0f / (float)NN);
#pragma unroll
        for (int off = 1; off < 64; off <<= 1) p += __shfl_xor(p, off);
        sc[r] = p;
    }
    if (lane == 0) {
        float m = fmaxf(sc[0], sc[1]);
        float e0 = expf(sc[0] - m), e1 = expf(sc[1] - m);
        attn[0] = e0 / (e0 + e1);
        attn[1] = e1 / (e0 + e1);
        m = fmaxf(sc[2], sc[3]);
        float f0 = expf(sc[2] - m), f1 = expf(sc[3] - m);
        attn[2] = f0 / (f0 + f1);
        attn[3] = f1 / (f0 + f1);
    }
}

// ---------------- combine: out = attn0*out_r0 + attn1*out_r1 (float32 output) ----------------
__global__ __launch_bounds__(256) void combine_kernel(
    const u16* __restrict__ outb, const float* __restrict__ attn, float* __restrict__ out)
{
    const int type = blockIdx.y;           // 0 = place (rels 2,3), 1 = trans (rels 0,1)
    const int r0 = (type == 0) ? 2 : 0;
    const float a0 = attn[r0], a1 = attn[r0 + 1];
    const ushort4* o0 = (const ushort4*)(outb + (size_t)r0 * NN * FO);
    const ushort4* o1 = (const ushort4*)(outb + (size_t)(r0 + 1) * NN * FO);
    float4* dst = (float4*)(out + (size_t)type * NN * FO);
    const int n4 = NN * FO / 4;
    const int stride = gridDim.x * 256;
    for (int i = blockIdx.x * 256 + threadIdx.x; i < n4; i += stride) {
        const ushort4 u = o0[i];
        const ushort4 w = o1[i];
        float4 r;
        r.x = a0 * bf2f(u.x) + a1 * bf2f(w.x);
        r.y = a0 * bf2f(u.y) + a1 * bf2f(w.y);
        r.z = a0 * bf2f(u.z) + a1 * bf2f(w.z);
        r.w = a0 * bf2f(u.w) + a1 * bf2f(w.w);
        dst[i] = r;
    }
}

extern "C" void kernel_launch(void* const* d_in, const int* in_sizes, int n_in,
                              void* d_out, int out_size, void* d_ws, size_t ws_size,
                              hipStream_t stream)
{
    const float* x_place = (const float*)d_in[0];
    const float* x_trans = (const float*)d_in[1];
    const float* W_place = (const float*)d_in[2];
    const float* b_place = (const float*)d_in[3];
    const float* W_trans = (const float*)d_in[4];
    const float* b_trans = (const float*)d_in[5];
    const float* as_pt = (const float*)d_in[6];
    const float* ad_pt = (const float*)d_in[7];
    const float* as_tp = (const float*)d_in[8];
    const float* ad_tp = (const float*)d_in[9];
    const float* as_pp = (const float*)d_in[10];
    const float* ad_pp = (const float*)d_in[11];
    const float* as_tt = (const float*)d_in[12];
    const float* ad_tt = (const float*)d_in[13];
    const float* q  = (const float*)d_in[14];
    const float* kW = (const float*)d_in[15];
    const float* kb = (const float*)d_in[16];
    const int* ei_pt = (const int*)d_in[17];
    const int* ei_tp = (const int*)d_in[18];
    const int* ei_pp = (const int*)d_in[19];
    const int* ei_tt = (const int*)d_in[20];

    // ---- workspace layout ----
    char* ws = (char*)d_ws;
    u16* hb_place = (u16*)ws;                                     // NN*64 bf16 = 12.8 MB
    u16* hb_trans = hb_place + (size_t)NN * FO;                   // 12.8 MB
    float* al_place = (float*)(hb_trans + (size_t)NN * FO);       // 4*NN*4 f32 = 6.4 MB
    float* al_trans = al_place + 4 * (size_t)NN * 4;              // 6.4 MB
    u16* outb = (u16*)(al_trans + 4 * (size_t)NN * 4);            // 4*NN*64 bf16 = 51.2 MB
    int* offs = (int*)(outb + 4 * (size_t)NN * FO);               // 4*(NN+1) int = 1.6 MB
    int* perm = offs + 4 * (size_t)(NN + 1);                      // 4*NE int = 16 MB
    u32* packed = (u32*)(perm + 4 * (size_t)NE);                  // 4*NE u32 = 16 MB
    int* bstart = (int*)(packed + 4 * (size_t)NE);                // 4*257 int
    int* bcursor = bstart + 4 * 257;                              // 4*256 int
    int* bucket_hist = bcursor + 4 * 256;                         // 4*256 int (zeroed region start)
    float* mean_acc = (float*)(bucket_hist + 4 * 256);            // 256 f32 (zeroed)
    float* attn = mean_acc + 256;                                 // 4 f32 (zeroed)

    // zero bucket_hist + mean_acc + attn in one shot
    hipMemsetAsync(bucket_hist, 0, (4 * 256 + 256 + 4) * sizeof(int), stream);

    // place node roles: src of pt, src of pp, dst of tp, dst of pp
    proj_kernel<<<1024, 256, 0, stream>>>(x_place, W_place, b_place,
                                          as_pt, as_pp, ad_tp, ad_pp,
                                          hb_place, al_place);
    // trans node roles: src of tp, src of tt, dst of pt, dst of tt
    proj_kernel<<<1024, 256, 0, stream>>>(x_trans, W_trans, b_trans,
                                          as_tp, as_tt, ad_pt, ad_tt,
                                          hb_trans, al_trans);

    csr_count<<<dim3(64, 4), 256, 0, stream>>>(ei_pt, ei_tt, ei_tp, ei_pp, bucket_hist);
    csr_base<<<4, 256, 0, stream>>>(bucket_hist, bstart, bcursor, offs);
    csr_place<<<dim3(64, 4), 256, 0, stream>>>(ei_pt, ei_tt, ei_tp, ei_pp, bcursor, packed);
    csr_build<<<dim3(NB, 4), 256, 0, stream>>>(packed, bstart, offs, perm);

    acc_kernel<<<dim3(1024, 4), 256, 0, stream>>>(hb_place, hb_trans, al_place, al_trans,
                                                  offs, perm, outb);

    sem_kernel<<<dim3(512, 4), 256, 0, stream>>>(outb, kW, kb, mean_acc);

    score_kernel<<<1, 64, 0, stream>>>(mean_acc, q, attn);

    combine_kernel<<<dim3(1024, 2), 256, 0, stream>>>(outb, attn, (float*)d_out);
}